// Round 11
// baseline (936.770 us; speedup 1.0000x reference)
//
#include <hip/hip_runtime.h>
#include <hip/hip_bf16.h>

typedef unsigned short ushort_t;
typedef unsigned int uint_t;
typedef unsigned long long u64_t;

#define BB 16
#define TE 128
#define TD 64
#define HH 256
#define G3 768
#define KK 256
#define OUTV 32000
#define MROWS_E (BB*TE)   // 2048
#define MROWS_D (BB*TD)   // 1024
#define NBLK 16           // GRU blocks (1 wave each); each owns JD h-dims
#define JD 16
#define QW_PER_BUF 2048   // {2xbf16, tag} qwords per h snapshot

typedef __attribute__((ext_vector_type(8))) short short8;
typedef __attribute__((ext_vector_type(4))) float f32x4;

__device__ __forceinline__ float b2f(ushort_t u) {
  union { uint_t i; float f; } v; v.i = ((uint_t)u) << 16; return v.f;
}
__device__ __forceinline__ ushort_t f2b(float f) {
  union { float f; uint_t i; } v; v.f = f;
  uint_t x = v.i;
  return (ushort_t)((x + 0x7fffu + ((x >> 16) & 1u)) >> 16);
}
// dtype-adaptive scalar load of a "float" input: f32f!=0 -> fp32 buffer, else bf16
__device__ __forceinline__ float ldf(const void* p, size_t i, uint_t f32f) {
  return f32f ? ((const float*)p)[i] : b2f(((const ushort_t*)p)[i]);
}
// fast, saturating sigmoid/tanh (inputs bounded; formulas robust at +-inf)
__device__ __forceinline__ float fsig(float x) { return 1.f/(1.f + __expf(-x)); }
__device__ __forceinline__ float ftanh(float x) { return 1.f - 2.f/(__expf(2.f*x) + 1.f); }

// ---------------------------------------------------------------------------
// prep: computes the dtype flag LOCALLY per block (detect_kernel folded in,
// one fewer launch); Whh -> bf16 [768][256]; dense_W -> bf16 transpose;
// out_W -> bf16 (VECTORIZED this round -- r10's scalar loop was the prime
// suspect for the +43us regression); combined gi biases; out bias -> fp32;
// zero tagged h-exchange buffer.
// ---------------------------------------------------------------------------
__global__ __launch_bounds__(256) void prep_kernel(
    const void* emb, const void* eWhh, const void* dWhh, const void* denseW,
    const void* outW, const void* ebih, const void* ebhh, const void* dbih,
    const void* dbhh, const void* outb, uint_t* flag,
    ushort_t* WBe, ushort_t* WBd, ushort_t* DWT, ushort_t* obW,
    float* cbe, float* cbd, float* obf, u64_t* hq) {
  // ---- dtype detect (verbatim logic, computed redundantly per block) ------
  int ltid = threadIdx.x;
  uint_t w = ((const uint_t*)emb)[ltid];
  uint_t e = (w >> 7) & 0xFFu;
  bool pass = (e >= 100u && e <= 127u);
  unsigned long long mb = __ballot(pass);
  __shared__ int cnt[4];
  if ((ltid & 63) == 0) cnt[ltid >> 6] = __popcll(mb);
  __syncthreads();
  int c = cnt[0] + cnt[1] + cnt[2] + cnt[3];
  uint_t f = (c >= 128) ? 0u : 1u;
  if (blockIdx.x == 0 && ltid == 0) *flag = f;   // for downstream kernels
  // ---- conversions --------------------------------------------------------
  int tid = blockIdx.x * blockDim.x + ltid;
  int nth = gridDim.x * blockDim.x;
  for (int i = tid; i < G3*KK; i += nth) {
    WBe[i] = f2b(ldf(eWhh, i, f));
    WBd[i] = f2b(ldf(dWhh, i, f));
  }
  for (int i = tid; i < 512*HH; i += nth) {
    int k = i / HH, cc = i % HH;
    DWT[i] = f2b(ldf(denseW, (size_t)cc*512 + k, f));
  }
  // out_W -> bf16, 8 elements per iteration (vectorized)
  const int OW8 = OUTV*HH/8;
  for (int i = tid; i < OW8; i += nth) {
    uint4 v;
    if (f) {
      const float4* s = (const float4*)outW + (size_t)i*2;
      float4 x = s[0], y = s[1];
      v.x = (uint_t)f2b(x.x) | ((uint_t)f2b(x.y) << 16);
      v.y = (uint_t)f2b(x.z) | ((uint_t)f2b(x.w) << 16);
      v.z = (uint_t)f2b(y.x) | ((uint_t)f2b(y.y) << 16);
      v.w = (uint_t)f2b(y.z) | ((uint_t)f2b(y.w) << 16);
    } else {
      v = ((const uint4*)outW)[i];
    }
    ((uint4*)obW)[i] = v;
  }
  for (int i = tid; i < G3; i += nth) {
    float be = ldf(ebih, i, f), bd = ldf(dbih, i, f);
    if (i < 2*HH) { be += ldf(ebhh, i, f); bd += ldf(dbhh, i, f); }
    cbe[i] = be; cbd[i] = bd;
  }
  for (int i = tid; i < OUTV; i += nth) obf[i] = ldf(outb, i, f);
  for (int i = tid; i < 2*QW_PER_BUF; i += nth) hq[i] = 0ull;  // tag0 + h=0
}

// ---------------------------------------------------------------------------
// Generic MFMA GEMM: C[m][n] = sum_k A[m][k]*B[n][k] (+bias[n]), K=256 fixed.
// (unchanged from round 10)
// ---------------------------------------------------------------------------
#define LDT 264

__global__ __launch_bounds__(256) void gemm_kernel(
    const ushort_t* A, const int* tokens, const void* emb,
    const void* Bw, int ldb, int b_off,
    const float* bias, const uint_t* flagp,
    float* Cf, ushort_t* Cb, int ldc, int M, int tshift, int a_f32, int b_bf16) {
  __shared__ __align__(16) ushort_t Bs[64*LDT];
  __shared__ __align__(16) ushort_t As[32*LDT];
  uint_t f = *flagp;
  int tid = threadIdx.x;
  int wave = tid >> 6, lane = tid & 63;
  int n0 = blockIdx.x * 64;
#pragma unroll
  for (int it = 0; it < 8; ++it) {
    int idx = it*256 + tid;
    int row = idx >> 5, col = (idx & 31) << 3;
    size_t e = (size_t)(n0 + row)*ldb + col + b_off;
    uint4 v;
    if (f && !b_bf16) {
      const float4* s = (const float4*)((const float*)Bw + e);
      float4 x = s[0], y = s[1];
      v.x = (uint_t)f2b(x.x) | ((uint_t)f2b(x.y) << 16);
      v.y = (uint_t)f2b(x.z) | ((uint_t)f2b(x.w) << 16);
      v.z = (uint_t)f2b(y.x) | ((uint_t)f2b(y.y) << 16);
      v.w = (uint_t)f2b(y.z) | ((uint_t)f2b(y.w) << 16);
    } else {
      v = *(const uint4*)((const ushort_t*)Bw + e);
    }
    *(uint4*)(Bs + row*LDT + col) = v;
  }
  int arow_i = lane & 15;
  float bias_v = 0.f;
  if (bias) bias_v = bias[n0 + wave*16 + arow_i];
  int koff = (lane >> 4) << 3;
  for (int m0 = blockIdx.y*32; m0 < M; m0 += gridDim.y*32) {
    __syncthreads();   // Bs ready / previous chunk compute done
#pragma unroll
    for (int it = 0; it < 4; ++it) {
      int idx = it*256 + tid;
      int row = idx >> 5, col = (idx & 31) << 3;
      uint4 v;
      if (tokens) {
        size_t e = (size_t)tokens[m0 + row]*KK + col;
        if (f) {
          const float4* s = (const float4*)((const float*)emb + e);
          float4 x = s[0], y = s[1];
          v.x = (uint_t)f2b(x.x) | ((uint_t)f2b(x.y) << 16);
          v.y = (uint_t)f2b(x.z) | ((uint_t)f2b(x.w) << 16);
          v.z = (uint_t)f2b(y.x) | ((uint_t)f2b(y.y) << 16);
          v.w = (uint_t)f2b(y.z) | ((uint_t)f2b(y.w) << 16);
        } else {
          v = *(const uint4*)((const ushort_t*)emb + e);
        }
      } else if (a_f32) {
        const float4* s = (const float4*)((const float*)A + (size_t)(m0 + row)*KK + col);
        float4 x = s[0], y = s[1];
        v.x = (uint_t)f2b(x.x) | ((uint_t)f2b(x.y) << 16);
        v.y = (uint_t)f2b(x.z) | ((uint_t)f2b(x.w) << 16);
        v.z = (uint_t)f2b(y.x) | ((uint_t)f2b(y.y) << 16);
        v.w = (uint_t)f2b(y.z) | ((uint_t)f2b(y.w) << 16);
      } else {
        v = *(const uint4*)(A + (size_t)(m0 + row)*KK + col);  // ws bf16
      }
      *(uint4*)(As + row*LDT + col) = v;
    }
    __syncthreads();
#pragma unroll
    for (int msub = 0; msub < 2; ++msub) {
      f32x4 acc = {0.f,0.f,0.f,0.f};
      const ushort_t* ap = As + (msub*16 + arow_i)*LDT + koff;
      const ushort_t* bp = Bs + (wave*16 + arow_i)*LDT + koff;
#pragma unroll
      for (int ks = 0; ks < 8; ++ks) {
        short8 af = *(const short8*)(ap + ks*32);
        short8 bf = *(const short8*)(bp + ks*32);
        acc = __builtin_amdgcn_mfma_f32_16x16x32_bf16(af, bf, acc, 0, 0, 0);
      }
      int mbase = m0 + msub*16 + (lane >> 4)*4;
      int ncol = n0 + wave*16 + arow_i;
#pragma unroll
      for (int r = 0; r < 4; ++r) {
        float val = acc[r] + bias_v;
        int mr = mbase + r;
        int orow = tshift ? (((mr & ((1 << tshift) - 1)) << 4) + (mr >> tshift)) : mr;
        if (Cf) Cf[(size_t)orow*ldc + ncol] = val;
        else    Cb[(size_t)orow*ldc + ncol] = f2b(val);
      }
    }
  }
}

// ---------------------------------------------------------------------------
// Multi-CU MFMA GRU, round 11: ONE WAVE PER REGION, ZERO BARRIERS.
//
// Round-10 counters: 16x256 gru at 333us, CUs ~88% idle. The step chain has
// two structural taxes: the mid-step __syncthreads couples 4 waves (block
// advances at MAX of 4 poll-detect times -> skew compounds each step), and
// the LDS partial-reduce adds ~400cy. Both exist only because a wave's
// K-slice was 64. This round: 16 blocks x 64 threads; each WAVE owns 16 dims,
// keeps its 48 Whh rows LDS-resident (24.75KB), polls all 32 tagged qwords
// it needs (full h; same aggregate traffic as before -- waves previously
// partitioned the same reads), runs the complete K=256 x 3-gate MFMA chain
// in-wave (24 MFMAs, K-accumulated in acc -- no cross-wave reduce), does EW
// for (4 batches x 1 dim)/lane, publishes 4 tagged qwords. NO barriers, no
// part[] LDS, no max-of-4 coupling.
//
// Layout (both sides redesigned, bijection verified):
//   publisher: region w, local pair lp, batch m -> qidx = w*128 + lp*16 + m
//   reader: lane (arow=lane&15 -> batch, quad), slice ks, elem e ->
//           qidx = ks*256 + quad*64 + e*16 + arow  (4x128B runs per load)
//   giving A-frag k = ks*32 + quad*8 + 2e(+1)  (same r6 fragment convention).
// Tag protocol, double-buffered hq, bounded guard, and the write-after-read
// safety proof carry over verbatim (now per-wave: every wave polls ALL
// regions each step, so observed tag s+1 in region V implies V finished
// reading buf[s&1]).  __launch_bounds__(64,1) -> 512-reg budget; live set
// ~140 VGPRs (qv 64 + acc 12 + gi 12 + misc).
// FALSIFICATION: if gru >= 300us, RTT itself is the floor -> revert to r10.
// ---------------------------------------------------------------------------
#define HSBF 264            // LDS row stride (bf16 elems): <=2-way banks on b128

__device__ __forceinline__ void stage_w64(const ushort_t* WB, int j0, int lane,
                                          ushort_t* wlds) {
#pragma unroll
  for (int it = 0; it < 24; ++it) {
    int idx = it*64 + lane;
    int row = idx >> 5, col = (idx & 31) << 3;   // row 0..47, col 0..255 step 8
    const ushort_t* src = WB + ((size_t)((row >> 4)*HH + j0 + (row & 15)))*KK + col;
    *(uint4*)(wlds + row*HSBF + col) = *(const uint4*)src;
  }
}

__global__ __launch_bounds__(64, 1) void gru_kernel(
    const float* gi_e, const float* gi_d, const ushort_t* WBe, const ushort_t* WBd,
    const void* ebhh, const void* dbhh, const uint_t* flagp,
    const int* elen, const int* dlen, float* eout, float* dout, u64_t* hq) {
  uint_t f = *flagp;
  __shared__ __align__(16) ushort_t wlds[48*HSBF];   // 24.75 KB
  const int lane = threadIdx.x;
  const int l15 = lane & 15, quad = lane >> 4;
  const int wreg = blockIdx.x;
  const int j0 = wreg * JD;
  const int j = j0 + l15;                            // lane's owned dim

  stage_w64(WBe, j0, lane, wlds);
  const float bn_e = ldf(ebhh, 2*HH + j, f);
  const float bn_d = ldf(dbhh, 2*HH + j, f);
  int lene_r[4], lend_r[4];
#pragma unroll
  for (int r = 0; r < 4; ++r) {
    lene_r[r] = elen[quad*4 + r];
    lend_r[r] = dlen[quad*4 + r];
  }
  float hreg[4] = {0.f, 0.f, 0.f, 0.f};
  float gr[4], gz[4], gn[4];
#pragma unroll
  for (int r = 0; r < 4; ++r) {     // gi for s=0: row = (t=0)*BB + m
    const float* gp = gi_e + (size_t)(quad*4 + r)*G3;
    gr[r] = gp[j]; gz[r] = gp[HH + j]; gn[r] = gp[2*HH + j];
  }
  const int pubbase = wreg*128 + (l15 >> 1)*16 + quad*4;
  const bool dopub = !(l15 & 1);

  for (int s = 0; s < TE + TD; ++s) {
    if (s == TE) stage_w64(WBd, j0, lane, wlds);   // same-wave ds order: safe
    const bool enc = s < TE;
    const int t = enc ? s : s - TE;
    // ---- poll the full h snapshot (32 tagged qwords/lane, coalesced) -----
    const u64_t* hbR = hq + (size_t)(s & 1)*QW_PER_BUF + quad*64 + l15;
    u64_t qv[32];
    const uint_t target = (uint_t)s;
    int guard = 0;
    for (;;) {
      bool ok = true;
#pragma unroll
      for (int ks = 0; ks < 8; ++ks)
#pragma unroll
        for (int e = 0; e < 4; ++e) {
          qv[ks*4 + e] = __hip_atomic_load(hbR + ks*256 + e*16,
                                           __ATOMIC_RELAXED, __HIP_MEMORY_SCOPE_AGENT);
          ok = ok && ((uint_t)qv[ks*4 + e] == target);
        }
      if (__all(ok) || ++guard > 30000) break;   // bounded (r3 lesson)
    }
    // ---- MFMA: full K=256, 3 gates, K-accumulated in-wave ----------------
    f32x4 ar = {0.f,0.f,0.f,0.f}, az = {0.f,0.f,0.f,0.f}, an = {0.f,0.f,0.f,0.f};
#pragma unroll
    for (int ks = 0; ks < 8; ++ks) {
      union { uint_t u[4]; short8 s8; } av;
#pragma unroll
      for (int e = 0; e < 4; ++e) av.u[e] = (uint_t)(qv[ks*4 + e] >> 32);
      const ushort_t* wp = wlds + l15*HSBF + ks*32 + quad*8;
      short8 b0 = *(const short8*)(wp);
      short8 b1 = *(const short8*)(wp + 16*HSBF);
      short8 b2 = *(const short8*)(wp + 32*HSBF);
      ar = __builtin_amdgcn_mfma_f32_16x16x32_bf16(av.s8, b0, ar, 0, 0, 0);
      az = __builtin_amdgcn_mfma_f32_16x16x32_bf16(av.s8, b1, az, 0, 0, 0);
      an = __builtin_amdgcn_mfma_f32_16x16x32_bf16(av.s8, b2, an, 0, 0, 0);
    }
    // ---- EW: lane owns dim j, batches m = quad*4 + r ---------------------
    const float bn = enc ? bn_e : bn_d;
#pragma unroll
    for (int r = 0; r < 4; ++r) {
      float rr = fsig(gr[r] + ar[r]);               // bih+bhh pre-folded in gi
      float zz = fsig(gz[r] + az[r]);
      float nn = ftanh(gn[r] + rr*(an[r] + bn));
      float hc = (1.f - zz)*nn + zz*hreg[r];
      bool valid = t < (enc ? lene_r[r] : lend_r[r]);
      float ov = valid ? hc : 0.f;
      hreg[r] = valid ? hc : hreg[r];
      int m = quad*4 + r;
      if (enc) eout[((size_t)(m*TE + t))*HH + j] = ov;
      else     dout[((size_t)(m*TD + t))*HH + j] = ov;
    }
    // ---- publish 4 tagged qwords (even-l15 lanes), fire-and-forget -------
    uint_t h16[4], up[4];
#pragma unroll
    for (int r = 0; r < 4; ++r) {
      h16[r] = (uint_t)f2b(hreg[r]);
      up[r] = (uint_t)__shfl_down((int)h16[r], 1);  // dim j+1, same quad
    }
    if (dopub) {
      u64_t* hbW = hq + (size_t)((s + 1) & 1)*QW_PER_BUF + pubbase;
#pragma unroll
      for (int r = 0; r < 4; ++r) {
        u64_t q = ((u64_t)(h16[r] | (up[r] << 16)) << 32) | (u64_t)(uint_t)(s + 1);
        __hip_atomic_store(hbW + r, q, __ATOMIC_RELAXED, __HIP_MEMORY_SCOPE_AGENT);
      }
    }
    // ---- prefetch next step's gi (overlaps next poll) --------------------
    int s2 = s + 1;
    if (s2 < TE + TD) {
      const float* gbase = (s2 < TE) ? gi_e + (size_t)(s2*BB)*G3
                                     : gi_d + (size_t)((s2 - TE)*BB)*G3;
#pragma unroll
      for (int r = 0; r < 4; ++r) {
        const float* gp = gbase + (size_t)(quad*4 + r)*G3;
        gr[r] = gp[j]; gz[r] = gp[HH + j]; gn[r] = gp[2*HH + j];
      }
    }
  }
}

// ---------------------------------------------------------------------------
// Attention + dense, one block per (b, td). (unchanged from round 8/10)
// ---------------------------------------------------------------------------
__global__ __launch_bounds__(256) void attn_kernel(
    const float* eprj, const float* dprj, const float* eout, const float* dout,
    const void* Wb, const void* av, const void* avb,
    const ushort_t* DWT, const void* db, const uint_t* flagp,
    const int* elen, const int* dlen, ushort_t* dense_bf) {
  int bd = blockIdx.x;
  int b = bd / TD, td = bd % TD;
  int tid = threadIdx.x;
  int wave = tid >> 6, lane = tid & 63;
  uint_t f = *flagp;
  __shared__ float dp[HH], dsrow[HH], vv[HH], att[TE];
  int el = elen[b];
  bool dok = td < dlen[b];   // uniform per block
  size_t drow = (size_t)bd * HH;
  dp[tid] = dprj[drow + tid] + ldf(Wb, tid, f);
  dsrow[tid] = dout[drow + tid];
  vv[tid] = ldf(av, tid, f);
  if (tid < TE) att[tid] = 0.f;    // weights default 0 (te >= el / invalid td)
  __syncthreads();
  float ctx = 0.f;
  if (dok) {
    float vb0 = ldf(avb, 0, f);
    int nteb = (el + 3) >> 2;
    for (int teb = 0; teb < nteb; ++teb) {
      int te = teb*4 + wave;          // wave-uniform
      if (te < el) {
        const float* ep = eprj + (size_t)(b*TE + te)*HH;
        float s = 0.f;
#pragma unroll
        for (int i = 0; i < 4; ++i) {
          int hh = lane + 64*i;
          s += ftanh(ep[hh] + dp[hh]) * vv[hh];
        }
#pragma unroll
        for (int off = 32; off > 0; off >>= 1) s += __shfl_xor(s, off);
        if (lane == 0) att[te] = s + vb0;
      }
    }
    __syncthreads();
    float mx = -1e30f;
    for (int te = 0; te < el; ++te) mx = fmaxf(mx, att[te]);
    __syncthreads();                 // all reads of raw energies done
    if (tid < el) att[tid] = __expf(att[tid] - mx);
    __syncthreads();
    float ssum = 0.f;
    for (int te = 0; te < el; ++te) ssum += att[te];
    float inv = (ssum > 0.f) ? 1.f/ssum : 0.f;
    const float* ebase = eout + (size_t)(b*TE)*HH + tid;
    float c0 = 0.f, c1 = 0.f, c2 = 0.f, c3 = 0.f;
    int te = 0;
    for (; te + 4 <= el; te += 4) {
      c0 += att[te    ] * ebase[(size_t)(te    )*HH];
      c1 += att[te + 1] * ebase[(size_t)(te + 1)*HH];
      c2 += att[te + 2] * ebase[(size_t)(te + 2)*HH];
      c3 += att[te + 3] * ebase[(size_t)(te + 3)*HH];
    }
    for (; te < el; ++te) c0 += att[te] * ebase[(size_t)te*HH];
    ctx = (c0 + c1 + c2 + c3) * inv;
  }
  __syncthreads();                   // att/dp reads done before dp reuse
  dp[tid] = ctx;                     // reuse dp as context
  __syncthreads();
  const ushort_t* w0 = DWT + tid;
  float a0 = ldf(db, tid, f), a1 = 0.f, a2 = 0.f, a3 = 0.f;
#pragma unroll 8
  for (int k = 0; k < HH; k += 4) {
    a0 = fmaf(b2f(w0[(size_t)(k    )*HH]), dsrow[k    ], a0);
    a1 = fmaf(b2f(w0[(size_t)(k + 1)*HH]), dsrow[k + 1], a1);
    a2 = fmaf(b2f(w0[(size_t)(k + 2)*HH]), dsrow[k + 2], a2);
    a3 = fmaf(b2f(w0[(size_t)(k + 3)*HH]), dsrow[k + 3], a3);
  }
#pragma unroll 8
  for (int k = 0; k < HH; k += 4) {
    a0 = fmaf(b2f(w0[(size_t)(HH + k    )*HH]), dp[k    ], a0);
    a1 = fmaf(b2f(w0[(size_t)(HH + k + 1)*HH]), dp[k + 1], a1);
    a2 = fmaf(b2f(w0[(size_t)(HH + k + 2)*HH]), dp[k + 2], a2);
    a3 = fmaf(b2f(w0[(size_t)(HH + k + 3)*HH]), dp[k + 3], a3);
  }
  dense_bf[drow + tid] = f2b(ftanh(a0 + a1 + a2 + a3));
}

// ---------------------------------------------------------------------------
extern "C" void kernel_launch(void* const* d_in, const int* in_sizes, int n_in,
                              void* d_out, int out_size, void* d_ws, size_t ws_size,
                              hipStream_t stream) {
  const int* enc_in   = (const int*)d_in[0];
  const int* enc_len  = (const int*)d_in[1];
  const int* dec_in   = (const int*)d_in[2];
  const int* dec_len  = (const int*)d_in[3];
  const void* emb    = d_in[4];
  const void* eWih   = d_in[5];
  const void* eWhh   = d_in[6];
  const void* ebih   = d_in[7];
  const void* ebhh   = d_in[8];
  const void* dWih   = d_in[9];
  const void* dWhh   = d_in[10];
  const void* dbih   = d_in[11];
  const void* dbhh   = d_in[12];
  const void* attnW  = d_in[13];
  const void* attnWb = d_in[14];
  const void* attnv  = d_in[15];
  const void* attnvb = d_in[16];
  const void* denseW = d_in[17];
  const void* denseb = d_in[18];
  const void* outW   = d_in[19];
  const void* outb   = d_in[20];
  float* out = (float*)d_out;   // reference output is fp32

  float* ws = (float*)d_ws;
  size_t o = 0;
  uint_t* flag = (uint_t*)(ws + o);   o += 4;
  u64_t* hq = (u64_t*)(ws + o);       o += 4*QW_PER_BUF;  // 2 bufs x 2048 qwords
  ushort_t* WBe = (ushort_t*)(ws + o); o += G3*KK/2;
  ushort_t* WBd = (ushort_t*)(ws + o); o += G3*KK/2;
  ushort_t* DWT = (ushort_t*)(ws + o); o += 512*HH/2;
  ushort_t* obW = (ushort_t*)(ws + o); o += (size_t)OUTV*HH/2;  // bf16 out_W
  float* cbe = ws + o;                o += G3;
  float* cbd = ws + o;                o += G3;
  float* obf = ws + o;                o += OUTV;
  float* gi_e = ws + o;               o += (size_t)MROWS_E*G3;   // (t,b)-interleaved
  float* gi_d = ws + o;               o += (size_t)MROWS_D*G3;   // (t,b)-interleaved
  float* eout = ws + o;               o += (size_t)MROWS_E*HH;
  float* dout = ws + o;               o += (size_t)MROWS_D*HH;
  float* eprj = ws + o;               o += (size_t)MROWS_E*HH;
  float* dprj = ws + o;               o += (size_t)MROWS_D*HH;
  ushort_t* dense_bf = (ushort_t*)(ws + o); o += (size_t)MROWS_D*HH/2;

  prep_kernel<<<384, 256, 0, stream>>>(emb, eWhh, dWhh, denseW, outW, ebih, ebhh,
                                       dbih, dbhh, outb, flag, WBe, WBd, DWT, obW,
                                       cbe, cbd, obf, hq);
  // gi = emb[tokens] @ Wih.T + (bih + bhh[r,z]), rows (t,b)-interleaved
  gemm_kernel<<<dim3(12,8), 256, 0, stream>>>(nullptr, enc_in, emb, eWih, 256, 0,
                                              cbe, flag, gi_e, nullptr, G3, MROWS_E, 7, 0, 0);
  gemm_kernel<<<dim3(12,4), 256, 0, stream>>>(nullptr, dec_in, emb, dWih, 256, 0,
                                              cbd, flag, gi_d, nullptr, G3, MROWS_D, 6, 0, 0);
  gru_kernel<<<NBLK, 64, 0, stream>>>(gi_e, gi_d, WBe, WBd, ebhh, dbhh, flag,
                                      enc_len, dec_len, eout, dout, hq);
  // enc_proj = enc_out @ W1.T ; dec_proj = dec_out @ W2.T  (attn_W col split)
  gemm_kernel<<<dim3(4,16), 256, 0, stream>>>((const ushort_t*)eout, nullptr, nullptr,
                                              attnW, 512, 0, nullptr, flag, eprj,
                                              nullptr, HH, MROWS_E, 0, 1, 0);
  gemm_kernel<<<dim3(4,8), 256, 0, stream>>>((const ushort_t*)dout, nullptr, nullptr,
                                             attnW, 512, 256, nullptr, flag, dprj,
                                             nullptr, HH, MROWS_D, 0, 1, 0);
  attn_kernel<<<MROWS_D, 256, 0, stream>>>(eprj, dprj, eout, dout, attnWb, attnv, attnvb,
                                           DWT, denseb, flag, enc_len, dec_len, dense_bf);
  // logits = dense @ out_W.T + out_b  (fp32 out; B pre-converted to bf16)
  gemm_kernel<<<dim3(500,4), 256, 0, stream>>>(dense_bf, nullptr, nullptr, obW, 256, 0,
                                               obf, flag, out, nullptr, OUTV, MROWS_D, 0, 0, 1);
}